// Round 9
// baseline (144.628 us; speedup 1.0000x reference)
//
#include <hip/hip_runtime.h>
#include <hip/hip_bf16.h>

#define LRELU_ALPHA 0.2f

constexpr int N   = 8192;
constexpr int FIN = 512;
constexpr int F   = 128;
constexpr int BRW = 16;          // rows per wave
constexpr int BR  = 64;          // rows per block (4 waves)
constexpr int BK  = 64;          // j per tile (2 MFMA k-steps, 1 mask u64)

typedef __attribute__((ext_vector_type(4))) float f32x4;
typedef __attribute__((ext_vector_type(8))) short s16x8;
typedef unsigned long long u64;

static __device__ __forceinline__ short f2bf(float x) {
  unsigned u = __float_as_uint(x);
  return (short)((u + 0x7fffu + ((u >> 16) & 1u)) >> 16);   // RNE bf16
}

// lgkm-only tile barrier: orders LDS writes/reads across waves WITHOUT
// draining vmcnt -> in-flight global (adj prefetch) loads survive.
static __device__ __forceinline__ void tile_barrier() {
  asm volatile("s_waitcnt lgkmcnt(0)" ::: "memory");
  __builtin_amdgcn_sched_barrier(0);
  __builtin_amdgcn_s_barrier();
  __builtin_amdgcn_sched_barrier(0);
}

// ---------------------------------------------------------------------------
// K1: WhbT = (h@w)^T bf16 [F][N]; Wh1 = Wh@a[:128]; Wh2 = Wh@a[128:] (f32).
// 512 threads, 32x128 tile, K chunks of 64 in LDS.
// ---------------------------------------------------------------------------
__global__ __launch_bounds__(512) void k_wh(
    const float* __restrict__ h, const float* __restrict__ w,
    const float* __restrict__ a, __hip_bfloat16* __restrict__ WhbT,
    float* __restrict__ Wh1, float* __restrict__ Wh2) {
  __shared__ float hl[32][68];
  __shared__ float wl[64][128];
  const int t    = threadIdx.x;
  const int i0   = blockIdx.x * 32;
  const int col4 = (t & 31) * 4;
  const int rq   = t >> 5;              // 0..15 -> rows rq*2, rq*2+1
  float acc[2][4] = {};

  for (int k0 = 0; k0 < FIN; k0 += 64) {
    *(f32x4*)&hl[t >> 4][(t & 15) * 4] =
        *(const f32x4*)(h + (size_t)(i0 + (t >> 4)) * FIN + k0 + (t & 15) * 4);
#pragma unroll
    for (int j = 0; j < 4; ++j) {
      int c = t + 512 * j;
      int kr = c >> 5, f4 = (c & 31) * 4;
      *(f32x4*)&wl[kr][f4] = *(const f32x4*)(w + (size_t)(k0 + kr) * F + f4);
    }
    __syncthreads();
#pragma unroll 4
    for (int k4 = 0; k4 < 64; k4 += 4) {
      f32x4 wv[4];
#pragma unroll
      for (int u = 0; u < 4; ++u) wv[u] = *(const f32x4*)&wl[k4 + u][col4];
#pragma unroll
      for (int ri = 0; ri < 2; ++ri) {
        f32x4 hv = *(const f32x4*)&hl[rq * 2 + ri][k4];
#pragma unroll
        for (int u = 0; u < 4; ++u) {
#pragma unroll
          for (int ci = 0; ci < 4; ++ci) acc[ri][ci] += hv[u] * wv[u][ci];
        }
      }
    }
    __syncthreads();
  }
#pragma unroll
  for (int ci = 0; ci < 4; ++ci) {
    int f = col4 + ci;
    unsigned pk = (unsigned)(unsigned short)f2bf(acc[0][ci]) |
                  ((unsigned)(unsigned short)f2bf(acc[1][ci]) << 16);
    *(unsigned*)((short*)WhbT + (size_t)f * N + i0 + rq * 2) = pk;
  }
  f32x4 av1 = *(const f32x4*)(a + col4);
  f32x4 av2 = *(const f32x4*)(a + F + col4);
  float s1[2], s2[2];
#pragma unroll
  for (int ri = 0; ri < 2; ++ri) {
    s1[ri] = acc[ri][0] * av1[0] + acc[ri][1] * av1[1] +
             acc[ri][2] * av1[2] + acc[ri][3] * av1[3];
    s2[ri] = acc[ri][0] * av2[0] + acc[ri][1] * av2[1] +
             acc[ri][2] * av2[2] + acc[ri][3] * av2[3];
  }
#pragma unroll
  for (int off = 1; off < 32; off <<= 1) {
#pragma unroll
    for (int ri = 0; ri < 2; ++ri) {
      s1[ri] += __shfl_xor(s1[ri], off);
      s2[ri] += __shfl_xor(s2[ri], off);
    }
  }
  if ((t & 31) == 0) {
#pragma unroll
    for (int ri = 0; ri < 2; ++ri) {
      Wh1[i0 + rq * 2 + ri] = s1[ri];
      Wh2[i0 + rq * 2 + ri] = s2[ri];
    }
  }
}

// ---------------------------------------------------------------------------
// K2: fused GAT attention partials; adj streamed inside the loop; the tile
// barrier is lgkm-only so adj prefetch (issued 1.5 phases ahead) crosses
// barriers and drains at its counted-vmcnt ballot consumer. Masks live in
// registers (ballot result kept where r == lane&15) -- no LDS mask traffic.
// Per-tile VMEM, FIFO order: sv (4, L2) then adj (16, HBM); ds_write(sv)
// waits vmcnt(16) leaving adj in flight. B-tile double-buffered XOR-swizzled
// LDS. Wh2 in LDS (lgkm path).
// ---------------------------------------------------------------------------
template <int KS>
__global__ __launch_bounds__(256) __attribute__((amdgpu_waves_per_eu(1, 4)))
void k_attn(
    const int* __restrict__ adj, const float* __restrict__ Wh1v,
    const float* __restrict__ Wh2v, const __hip_bfloat16* __restrict__ WhbT,
    float* __restrict__ accP, float* __restrict__ lP) {
  constexpr int JW  = N / KS;
  constexpr int NTL = JW / BK;     // 16 for KS=8 (even, >=4)
  __shared__ __align__(16) short Bl[2][F * BK];   // 2 x 16 KB
  __shared__ float w2l[JW];

  const int t   = threadIdx.x;
  const int l   = t & 63;
  const int w   = t >> 6;
  const int r16 = l & 15;
  const int g8  = (l >> 4) * 8;
  const int i0  = blockIdx.x * BR;
  const int s   = blockIdx.y;

  const int row  = i0 + w * BRW + r16;
  const float w1 = Wh1v[row];
  const int* __restrict__ rp_w   = adj + (size_t)(i0 + w * BRW) * N +
                                   (size_t)s * JW;   // wave's 16 rows
  const float* __restrict__ w2p  = Wh2v + (size_t)s * JW;
  const short* __restrict__ bsrc = (const short*)WhbT + (size_t)s * JW;

  // staging map: chunk c = t + 256*q (16 B each); row fr = c>>3
  int ldsoff[4]; size_t goff[4];
#pragma unroll
  for (int q = 0; q < 4; ++q) {
    int c  = t + 256 * q;
    int fr = c >> 3;
    ldsoff[q] = (c * 16) ^ ((fr & 7) << 4);           // swizzled LDS byte
    goff[q]   = (size_t)fr * N + (c & 7) * 8;         // linear global (shorts)
  }
  const int sw = (r16 & 7) << 4;                       // read-side XOR

  f32x4 acc[8] = {};
  float lsum = 0.f;
  s16x8 sv[4];
  int bufA[16], bufB[16];
  u64 mcur;                        // mask for the tile about to be scored

  auto adj_issue = [&](int (&vv)[16], int tile) {
#pragma unroll
    for (int r = 0; r < 16; ++r)
      vv[r] = rp_w[(size_t)r * N + (size_t)tile * BK + l];
  };
  // ballot the 16 rows; lane l keeps the mask of its own row (l&15)
  auto ballot_mask = [&](const int (&vv)[16]) -> u64 {
    u64 msk = 0;
#pragma unroll
    for (int r = 0; r < 16; ++r) {
      u64 m = __ballot(vv[r] > 0);
      if (r16 == r) msk = m;
    }
    return msk;
  };

  auto scores = [&](int tl, u64 m, s16x8& af0, s16x8& af1) {
    const f32x4 y0 = *(const f32x4*)&w2l[tl * BK + g8];
    const f32x4 y1 = *(const f32x4*)&w2l[tl * BK + g8 + 4];
    const f32x4 y2 = *(const f32x4*)&w2l[tl * BK + g8 + 32];
    const f32x4 y3 = *(const f32x4*)&w2l[tl * BK + g8 + 36];
    const unsigned b0 = (unsigned)(m >> g8) & 0xffu;
    const unsigned b1 = (unsigned)(m >> (g8 + 32)) & 0xffu;
    float p[16];
#pragma unroll
    for (int u = 0; u < 4; ++u) {
      float x = w1 + y0[u]; x = fmaxf(x, LRELU_ALPHA * x);
      p[u] = (b0 >> u) & 1u ? __expf(x) : 0.f;
    }
#pragma unroll
    for (int u = 0; u < 4; ++u) {
      float x = w1 + y1[u]; x = fmaxf(x, LRELU_ALPHA * x);
      p[4 + u] = (b0 >> (4 + u)) & 1u ? __expf(x) : 0.f;
    }
#pragma unroll
    for (int u = 0; u < 4; ++u) {
      float x = w1 + y2[u]; x = fmaxf(x, LRELU_ALPHA * x);
      p[8 + u] = (b1 >> u) & 1u ? __expf(x) : 0.f;
    }
#pragma unroll
    for (int u = 0; u < 4; ++u) {
      float x = w1 + y3[u]; x = fmaxf(x, LRELU_ALPHA * x);
      p[12 + u] = (b1 >> (4 + u)) & 1u ? __expf(x) : 0.f;
    }
#pragma unroll
    for (int u = 0; u < 16; ++u) lsum += p[u];
    af0 = s16x8{f2bf(p[0]),  f2bf(p[1]),  f2bf(p[2]),  f2bf(p[3]),
                f2bf(p[4]),  f2bf(p[5]),  f2bf(p[6]),  f2bf(p[7])};
    af1 = s16x8{f2bf(p[8]),  f2bf(p[9]),  f2bf(p[10]), f2bf(p[11]),
                f2bf(p[12]), f2bf(p[13]), f2bf(p[14]), f2bf(p[15])};
  };

  auto mfma_tile = [&](const char* pb, s16x8 af0, s16x8 af1) {
#pragma unroll
    for (int nb = 0; nb < 8; ++nb) {
      const int rbase = (nb * 16 + r16) * 128;
      s16x8 b0 = *(const s16x8*)(pb + rbase + ((g8 * 2) ^ sw));
      s16x8 b1 = *(const s16x8*)(pb + rbase + ((g8 * 2 + 64) ^ sw));
      acc[nb] = __builtin_amdgcn_mfma_f32_16x16x32_bf16(af0, b0, acc[nb], 0, 0, 0);
      acc[nb] = __builtin_amdgcn_mfma_f32_16x16x32_bf16(af1, b1, acc[nb], 0, 0, 0);
    }
  };

  // ---- prologue: w2l -> LDS; stage tile 0 -> Bl[0]; adj tiles 0,1 -> regs --
  for (int j4 = t; j4 * 4 < JW; j4 += 256)
    *(f32x4*)&w2l[j4 * 4] = *(const f32x4*)(w2p + j4 * 4);
#pragma unroll
  for (int q = 0; q < 4; ++q) sv[q] = *(const s16x8*)(bsrc + goff[q]);
  adj_issue(bufA, 0);
  adj_issue(bufB, 1);
#pragma unroll
  for (int q = 0; q < 4; ++q)
    *(s16x8*)((char*)&Bl[0][0] + ldsoff[q]) = sv[q];
  mcur = ballot_mask(bufA);        // mask(0)
  __syncthreads();                 // one-time full drain: fine

  for (int tl = 0; tl < NTL; tl += 2) {
    // ---- even tile tl: uses mcur; bufA <- adj(tl+2); mcur <- mask(tl+1) ---
    {
#pragma unroll
      for (int q = 0; q < 4; ++q)
        sv[q] = *(const s16x8*)(bsrc + goff[q] + (size_t)(tl + 1) * BK);
      if (tl + 2 < NTL) adj_issue(bufA, tl + 2);
      s16x8 af0, af1;
      scores(tl, mcur, af0, af1);
#pragma unroll
      for (int q = 0; q < 4; ++q)
        *(s16x8*)((char*)&Bl[1][0] + ldsoff[q]) = sv[q];   // vmcnt(16)
      mcur = ballot_mask(bufB);                            // mask(tl+1)
      mfma_tile((const char*)&Bl[0][0], af0, af1);
    }
    tile_barrier();
    // ---- odd tile tl+1: uses mcur; bufB <- adj(tl+3); mcur <- mask(tl+2) --
    {
      const size_t tn = (size_t)(tl + 2 < NTL ? tl + 2 : tl) * BK;  // dup ok
#pragma unroll
      for (int q = 0; q < 4; ++q)
        sv[q] = *(const s16x8*)(bsrc + goff[q] + tn);
      if (tl + 3 < NTL) adj_issue(bufB, tl + 3);
      s16x8 af0, af1;
      scores(tl + 1, mcur, af0, af1);
#pragma unroll
      for (int q = 0; q < 4; ++q)
        *(s16x8*)((char*)&Bl[0][0] + ldsoff[q]) = sv[q];
      mcur = ballot_mask(bufA);                            // mask(tl+2)
      mfma_tile((const char*)&Bl[1][0], af0, af1);
    }
    tile_barrier();
  }

  // row-sums: lanes {l, l^16, l^32, l^48} hold the row's k-slot partials
  lsum += __shfl_xor(lsum, 16);
  lsum += __shfl_xor(lsum, 32);
  if (l < 16) lP[(size_t)s * N + row] = lsum;
  // partial accumulator (C layout: row=(l>>4)*4+rg, col=l&15)
  float* op = accP + (size_t)s * N * F;
#pragma unroll
  for (int nb = 0; nb < 8; ++nb) {
#pragma unroll
    for (int rg = 0; rg < 4; ++rg) {
      int r = i0 + w * BRW + (l >> 4) * 4 + rg;
      op[(size_t)r * F + nb * 16 + r16] = acc[nb][rg];
    }
  }
}

// ---------------------------------------------------------------------------
// K3: combine partials: out = elu( (sum_s accP) / (sum_s lP) )
// ---------------------------------------------------------------------------
template <int KS>
__global__ __launch_bounds__(256) void k_comb(
    const float* __restrict__ accP, const float* __restrict__ lP,
    float* __restrict__ out) {
  const int idx = blockIdx.x * 256 + threadIdx.x;  // one f32x4 per thread
  const int i   = idx >> 5;                        // row (F/4 = 32 per row)
  f32x4 v = {};
  float lt = 0.f;
#pragma unroll
  for (int s = 0; s < KS; ++s) {
    v += *(const f32x4*)(accP + (size_t)s * N * F + (size_t)idx * 4);
    lt += lP[(size_t)s * N + i];
  }
  f32x4 o;
#pragma unroll
  for (int u = 0; u < 4; ++u) {
    float x = v[u] / lt;
    o[u] = x > 0.f ? x : __expf(x) - 1.f;          // ELU
  }
  *(f32x4*)(out + (size_t)idx * 4) = o;
}

// ---------------------------------------------------------------------------
extern "C" void kernel_launch(void* const* d_in, const int* in_sizes, int n_in,
                              void* d_out, int out_size, void* d_ws, size_t ws_size,
                              hipStream_t stream) {
  const float* h   = (const float*)d_in[0];
  const int*   adj = (const int*)d_in[1];
  const float* w   = (const float*)d_in[2];
  const float* a   = (const float*)d_in[3];
  float* out = (float*)d_out;

  // ws: WhbT bf16 [F][N] | Wh1 [N] | Wh2 [N] | lP [KS][N] | accP [KS][N][F]
  char* ws = (char*)d_ws;
  __hip_bfloat16* WhbT = (__hip_bfloat16*)ws;
  float* Wh1 = (float*)(ws + (size_t)F * N * 2);
  float* Wh2 = Wh1 + N;
  float* lP  = Wh2 + N;

  const size_t fixed = (size_t)F * N * 2 + 2 * (size_t)N * 4;
  const size_t need8 = fixed + 8 * (size_t)N * 4 + 8 * (size_t)N * F * 4;

  k_wh<<<N / 32, 512, 0, stream>>>(h, w, a, WhbT, Wh1, Wh2);
  if (ws_size >= need8) {
    constexpr int KS = 8;
    float* accP = lP + (size_t)KS * N;
    k_attn<KS><<<dim3(N / BR, KS), 256, 0, stream>>>(adj, Wh1, Wh2, WhbT,
                                                     accP, lP);
    k_comb<KS><<<(N * F / 4) / 256, 256, 0, stream>>>(accP, lP, out);
  } else {
    constexpr int KS = 4;
    float* accP = lP + (size_t)KS * N;
    k_attn<KS><<<dim3(N / BR, KS), 256, 0, stream>>>(adj, Wh1, Wh2, WhbT,
                                                     accP, lP);
    k_comb<KS><<<(N * F / 4) / 256, 256, 0, stream>>>(accP, lP, out);
  }
}

// Round 10
// 143.360 us; speedup vs baseline: 1.0088x; 1.0088x over previous
//
#include <hip/hip_runtime.h>
#include <hip/hip_bf16.h>

#define LRELU_ALPHA 0.2f

constexpr int N   = 8192;
constexpr int FIN = 512;
constexpr int F   = 128;
constexpr int BRW = 16;          // rows per wave
constexpr int BR  = 64;          // rows per block (4 waves)

typedef __attribute__((ext_vector_type(4))) float f32x4;
typedef __attribute__((ext_vector_type(8))) short s16x8;
typedef unsigned long long u64;

static __device__ __forceinline__ short f2bf(float x) {
  unsigned u = __float_as_uint(x);
  return (short)((u + 0x7fffu + ((u >> 16) & 1u)) >> 16);   // RNE bf16
}

// ---------------------------------------------------------------------------
// K1: Bpack = (h@w)^T bf16 in MFMA-fragment-packed layout; Wh1/Wh2 f32.
// Bpack short index: (kt*8 + nb)*512 + (kslot*16 + c)*8 + u
//   kt = j>>5 (32-j tile), nb = f>>4, c = f&15, kslot = (j>>3)&3, u = j&7.
// So k_attn's wave-lane l reads its B fragment as 16 contiguous bytes at
// base + l*16 -> perfectly coalesced 1 KB per load instruction.
// ---------------------------------------------------------------------------
__global__ __launch_bounds__(512) void k_wh(
    const float* __restrict__ h, const float* __restrict__ w,
    const float* __restrict__ a, short* __restrict__ Bpack,
    float* __restrict__ Wh1, float* __restrict__ Wh2) {
  __shared__ float hl[32][68];
  __shared__ float wl[64][128];
  const int t    = threadIdx.x;
  const int i0   = blockIdx.x * 32;
  const int col4 = (t & 31) * 4;
  const int rq   = t >> 5;              // 0..15 -> rows rq*2, rq*2+1
  float acc[2][4] = {};

  for (int k0 = 0; k0 < FIN; k0 += 64) {
    *(f32x4*)&hl[t >> 4][(t & 15) * 4] =
        *(const f32x4*)(h + (size_t)(i0 + (t >> 4)) * FIN + k0 + (t & 15) * 4);
#pragma unroll
    for (int j = 0; j < 4; ++j) {
      int c = t + 512 * j;
      int kr = c >> 5, f4 = (c & 31) * 4;
      *(f32x4*)&wl[kr][f4] = *(const f32x4*)(w + (size_t)(k0 + kr) * F + f4);
    }
    __syncthreads();
#pragma unroll 4
    for (int k4 = 0; k4 < 64; k4 += 4) {
      f32x4 wv[4];
#pragma unroll
      for (int u = 0; u < 4; ++u) wv[u] = *(const f32x4*)&wl[k4 + u][col4];
#pragma unroll
      for (int ri = 0; ri < 2; ++ri) {
        f32x4 hv = *(const f32x4*)&hl[rq * 2 + ri][k4];
#pragma unroll
        for (int u = 0; u < 4; ++u) {
#pragma unroll
          for (int ci = 0; ci < 4; ++ci) acc[ri][ci] += hv[u] * wv[u][ci];
        }
      }
    }
    __syncthreads();
  }
  // Bpack store: rows j = i0+rq*2 (+1) -> u, u+1 (u even) packed in one dword
  {
    const int kt    = blockIdx.x;        // i0>>5
    const int kslot = rq >> 2;
    const int u     = (rq * 2) & 7;
#pragma unroll
    for (int ci = 0; ci < 4; ++ci) {
      int f = col4 + ci;
      int nb = f >> 4, c = f & 15;
      unsigned pk = (unsigned)(unsigned short)f2bf(acc[0][ci]) |
                    ((unsigned)(unsigned short)f2bf(acc[1][ci]) << 16);
      size_t idx = (size_t)(kt * 8 + nb) * 512 + (kslot * 16 + c) * 8 + u;
      *(unsigned*)(Bpack + idx) = pk;
    }
  }
  f32x4 av1 = *(const f32x4*)(a + col4);
  f32x4 av2 = *(const f32x4*)(a + F + col4);
  float s1[2], s2[2];
#pragma unroll
  for (int ri = 0; ri < 2; ++ri) {
    s1[ri] = acc[ri][0] * av1[0] + acc[ri][1] * av1[1] +
             acc[ri][2] * av1[2] + acc[ri][3] * av1[3];
    s2[ri] = acc[ri][0] * av2[0] + acc[ri][1] * av2[1] +
             acc[ri][2] * av2[2] + acc[ri][3] * av2[3];
  }
#pragma unroll
  for (int off = 1; off < 32; off <<= 1) {
#pragma unroll
    for (int ri = 0; ri < 2; ++ri) {
      s1[ri] += __shfl_xor(s1[ri], off);
      s2[ri] += __shfl_xor(s2[ri], off);
    }
  }
  if ((t & 31) == 0) {
#pragma unroll
    for (int ri = 0; ri < 2; ++ri) {
      Wh1[i0 + rq * 2 + ri] = s1[ri];
      Wh2[i0 + rq * 2 + ri] = s2[ri];
    }
  }
}

// ---------------------------------------------------------------------------
// K2: fused GAT attention partials -- NO LDS staging, NO loop barriers.
// grid (128, KS), block 256 = 4 waves; wave owns 16 rows x 128 f, phases of
// 32 j. Per phase: issue 8 Bpack loads (phase+1, L2, coalesced 1KB/instr)
// and 8 adj loads (phase+2, HBM, 2x128B/instr); consume adj(t) via ballot
// (counted vmcnt, ~2-phase cover) and bf(t) via MFMA (~1.8-phase cover).
// Masks live in registers; Wh2 in LDS (lgkm path). vmcnt never drains to 0.
// ---------------------------------------------------------------------------
template <int KS>
__global__ __launch_bounds__(256) void k_attn(
    const int* __restrict__ adj, const float* __restrict__ Wh1v,
    const float* __restrict__ Wh2v, const short* __restrict__ Bpack,
    float* __restrict__ accP, float* __restrict__ lP) {
  constexpr int JW  = N / KS;
  constexpr int NTL = JW / 32;     // phases (32 for KS=8) -- even
  __shared__ float w2l[JW];

  const int t   = threadIdx.x;
  const int l   = t & 63;
  const int w   = t >> 6;
  const int r16 = l & 15;
  const int g8  = (l >> 4) * 8;
  const int q2  = l >> 5;          // row parity for adj loads
  const int j32 = l & 31;
  const int i0  = blockIdx.x * BR;
  const int s   = blockIdx.y;

  const int row  = i0 + w * BRW + r16;
  const float w1 = Wh1v[row];
  const int* __restrict__ rp = adj + (size_t)(i0 + w * BRW) * N +
                               (size_t)s * JW;          // wave's 16 rows
  const short* __restrict__ bq = Bpack + (size_t)s * NTL * 8 * 512 + l * 8;

  f32x4 acc[8] = {};
  float lsum = 0.f;
  int adjA[8], adjB[8];
  s16x8 bfA[8], bfB[8];

#define ADJ_LOAD(vv, tt)                                                     \
  _Pragma("unroll") for (int i = 0; i < 8; ++i)                              \
      vv[i] = rp[(size_t)(2 * i + q2) * N + (tt) * 32 + j32];
#define BF_LOAD(bf, tt)                                                      \
  _Pragma("unroll") for (int nb = 0; nb < 8; ++nb)                           \
      bf[nb] = *(const s16x8*)(bq + (size_t)((tt) * 8 + nb) * 512);

  // ballot the 16 rows (2 per instr); lane keeps the 8 bits (row r16,
  // j-slots g8..g8+7) it scores.
  auto mask_byte = [&](const int (&vv)[8]) -> unsigned {
    const unsigned sh = (unsigned)((r16 & 1) * 32 + g8);
    unsigned byte = 0;
#pragma unroll
    for (int i = 0; i < 8; ++i) {
      u64 m = __ballot(vv[i] > 0);
      unsigned b = (unsigned)(m >> sh) & 0xffu;
      byte = ((r16 >> 1) == i) ? b : byte;
    }
    return byte;
  };

  auto scores8 = [&](unsigned mb, int tt, s16x8& af) {
    const f32x4 y0 = *(const f32x4*)&w2l[tt * 32 + g8];
    const f32x4 y1 = *(const f32x4*)&w2l[tt * 32 + g8 + 4];
    float p[8];
#pragma unroll
    for (int u = 0; u < 4; ++u) {
      float x = w1 + y0[u]; x = fmaxf(x, LRELU_ALPHA * x);
      p[u] = (mb >> u) & 1u ? __expf(x) : 0.f;
    }
#pragma unroll
    for (int u = 0; u < 4; ++u) {
      float x = w1 + y1[u]; x = fmaxf(x, LRELU_ALPHA * x);
      p[4 + u] = (mb >> (4 + u)) & 1u ? __expf(x) : 0.f;
    }
#pragma unroll
    for (int u = 0; u < 8; ++u) lsum += p[u];
    af = s16x8{f2bf(p[0]), f2bf(p[1]), f2bf(p[2]), f2bf(p[3]),
               f2bf(p[4]), f2bf(p[5]), f2bf(p[6]), f2bf(p[7])};
  };

  // ---- prologue: Wh2 -> LDS; first adj/bf batches; one-time barrier ----
#pragma unroll
  for (int j4 = t; j4 < JW / 4; j4 += 256)
    *(f32x4*)&w2l[j4 * 4] = *(const f32x4*)(Wh2v + (size_t)s * JW + j4 * 4);
  ADJ_LOAD(adjA, 0)
  BF_LOAD(bfA, 0)
  ADJ_LOAD(adjB, 1)
  __syncthreads();                 // one-time full drain; regs stay valid

  for (int tt = 0; tt < NTL; tt += 2) {
    // ---- even phase tt: consume adjA/bfA; issue bfB(tt+1), adjA(tt+2) ----
    {
      BF_LOAD(bfB, tt + 1)                       // tt+1 < NTL (NTL even)
      unsigned mb = mask_byte(adjA);
      if (tt + 2 < NTL) ADJ_LOAD(adjA, tt + 2)
      s16x8 af;
      scores8(mb, tt, af);
#pragma unroll
      for (int nb = 0; nb < 8; ++nb)
        acc[nb] = __builtin_amdgcn_mfma_f32_16x16x32_bf16(af, bfA[nb],
                                                          acc[nb], 0, 0, 0);
    }
    // ---- odd phase tt+1: consume adjB/bfB; issue bfA(tt+2), adjB(tt+3) ----
    {
      if (tt + 2 < NTL) BF_LOAD(bfA, tt + 2)
      unsigned mb = mask_byte(adjB);
      if (tt + 3 < NTL) ADJ_LOAD(adjB, tt + 3)
      s16x8 af;
      scores8(mb, tt + 1, af);
#pragma unroll
      for (int nb = 0; nb < 8; ++nb)
        acc[nb] = __builtin_amdgcn_mfma_f32_16x16x32_bf16(af, bfB[nb],
                                                          acc[nb], 0, 0, 0);
    }
  }
#undef ADJ_LOAD
#undef BF_LOAD

  // row-sums: lanes {l, l^16, l^32, l^48} hold the row's j-slot partials
  lsum += __shfl_xor(lsum, 16);
  lsum += __shfl_xor(lsum, 32);
  if (l < 16) lP[(size_t)s * N + row] = lsum;
  // partial accumulator (C layout: row=(l>>4)*4+rg, col=l&15)
  float* op = accP + (size_t)s * N * F;
#pragma unroll
  for (int nb = 0; nb < 8; ++nb) {
#pragma unroll
    for (int rg = 0; rg < 4; ++rg) {
      int r = i0 + w * BRW + (l >> 4) * 4 + rg;
      op[(size_t)r * F + nb * 16 + r16] = acc[nb][rg];
    }
  }
}

// ---------------------------------------------------------------------------
// K3: combine partials: out = elu( (sum_s accP) / (sum_s lP) )
// ---------------------------------------------------------------------------
template <int KS>
__global__ __launch_bounds__(256) void k_comb(
    const float* __restrict__ accP, const float* __restrict__ lP,
    float* __restrict__ out) {
  const int idx = blockIdx.x * 256 + threadIdx.x;  // one f32x4 per thread
  const int i   = idx >> 5;                        // row (F/4 = 32 per row)
  f32x4 v = {};
  float lt = 0.f;
#pragma unroll
  for (int s = 0; s < KS; ++s) {
    v += *(const f32x4*)(accP + (size_t)s * N * F + (size_t)idx * 4);
    lt += lP[(size_t)s * N + i];
  }
  f32x4 o;
#pragma unroll
  for (int u = 0; u < 4; ++u) {
    float x = v[u] / lt;
    o[u] = x > 0.f ? x : __expf(x) - 1.f;          // ELU
  }
  *(f32x4*)(out + (size_t)idx * 4) = o;
}

// ---------------------------------------------------------------------------
extern "C" void kernel_launch(void* const* d_in, const int* in_sizes, int n_in,
                              void* d_out, int out_size, void* d_ws, size_t ws_size,
                              hipStream_t stream) {
  const float* h   = (const float*)d_in[0];
  const int*   adj = (const int*)d_in[1];
  const float* w   = (const float*)d_in[2];
  const float* a   = (const float*)d_in[3];
  float* out = (float*)d_out;

  // ws: Bpack bf16 (2 MB) | Wh1 [N] | Wh2 [N] | lP [KS][N] | accP [KS][N][F]
  char* ws = (char*)d_ws;
  short* Bpack = (short*)ws;
  float* Wh1 = (float*)(ws + (size_t)F * N * 2);
  float* Wh2 = Wh1 + N;
  float* lP  = Wh2 + N;

  const size_t fixed = (size_t)F * N * 2 + 2 * (size_t)N * 4;
  const size_t need8 = fixed + 8 * (size_t)N * 4 + 8 * (size_t)N * F * 4;

  k_wh<<<N / 32, 512, 0, stream>>>(h, w, a, Bpack, Wh1, Wh2);
  if (ws_size >= need8) {
    constexpr int KS = 8;
    float* accP = lP + (size_t)KS * N;
    k_attn<KS><<<dim3(N / BR, KS), 256, 0, stream>>>(adj, Wh1, Wh2, Bpack,
                                                     accP, lP);
    k_comb<KS><<<(N * F / 4) / 256, 256, 0, stream>>>(accP, lP, out);
  } else {
    constexpr int KS = 4;
    float* accP = lP + (size_t)KS * N;
    k_attn<KS><<<dim3(N / BR, KS), 256, 0, stream>>>(adj, Wh1, Wh2, Bpack,
                                                     accP, lP);
    k_comb<KS><<<(N * F / 4) / 256, 256, 0, stream>>>(accP, lP, out);
  }
}

// Round 11
// 137.311 us; speedup vs baseline: 1.0533x; 1.0441x over previous
//
#include <hip/hip_runtime.h>
#include <hip/hip_bf16.h>

#define LRELU_ALPHA 0.2f

constexpr int N   = 8192;
constexpr int FIN = 512;
constexpr int F   = 128;
constexpr int BRW = 16;          // rows per wave (attn)
constexpr int BR  = 64;          // rows per block (attn, 4 waves)

typedef __attribute__((ext_vector_type(4))) float f32x4;
typedef __attribute__((ext_vector_type(8))) short s16x8;
typedef unsigned long long u64;

static __device__ __forceinline__ short f2bf(float x) {
  unsigned u = __float_as_uint(x);
  return (short)((u + 0x7fffu + ((u >> 16) & 1u)) >> 16);   // RNE bf16
}

// ---------------------------------------------------------------------------
// K1 "producer", block-specialized 4:1.
//  - mask blocks (1024, bx%5!=4): ballot-compress adj -> bitmask[8192][128]
//    u64. Pure coalesced stream at HBM rate (R6-proven pattern).
//  - wh blocks (256, bx%5==4): Bpack = (h@w)^T bf16 fragment-packed;
//    Wh1 = Wh@a[:128]; Wh2 = Wh@a[128:]. Compute-bound, hides under stream.
// Bpack short index: (kt*8+nb)*512 + (kslot*16+c)*8 + u
//   kt=j>>5, nb=f>>4, c=f&15, kslot=(j>>3)&3, u=j&7  -> attn lane l reads
//   16 contiguous bytes at base + l*16 (coalesced 1KB/wave-instr).
// ---------------------------------------------------------------------------
__global__ __launch_bounds__(512) void k_prod(
    const float* __restrict__ h, const float* __restrict__ w,
    const float* __restrict__ a, const int* __restrict__ adj,
    short* __restrict__ Bpack, float* __restrict__ Wh1,
    float* __restrict__ Wh2, u64* __restrict__ mask) {
  const int bx = blockIdx.x;
  if ((bx % 5) != 4) {
    // ---------------- mask block: 8 rows, one per wave ----------------
    const int mask_id = (bx / 5) * 4 + (bx % 5);        // 0..1023
    const int l   = threadIdx.x & 63;
    const int row = mask_id * 8 + (threadIdx.x >> 6);
    const int* __restrict__ rp = adj + (size_t)row * N;
    u64* __restrict__ mp = mask + (size_t)row * (N / 64);
    for (int it = 0; it < N / 512; ++it) {              // 16 x 512 j
      int v[8];
#pragma unroll
      for (int k = 0; k < 8; ++k) v[k] = rp[it * 512 + l + k * 64];
      u64 m[8];
#pragma unroll
      for (int k = 0; k < 8; ++k) m[k] = __ballot(v[k] > 0);
      if (l == 0) {
        ulonglong2 s0 = {m[0], m[1]}, s1 = {m[2], m[3]};
        ulonglong2 s2 = {m[4], m[5]}, s3 = {m[6], m[7]};
        *(ulonglong2*)(mp + it * 8)     = s0;
        *(ulonglong2*)(mp + it * 8 + 2) = s1;
        *(ulonglong2*)(mp + it * 8 + 4) = s2;
        *(ulonglong2*)(mp + it * 8 + 6) = s3;
      }
    }
    return;
  }
  // ---------------- wh block: 32-row x 128-col GEMM tile ----------------
  __shared__ float hl[32][68];
  __shared__ float wl[64][128];
  const int t    = threadIdx.x;
  const int i0   = (bx / 5) * 32;
  const int col4 = (t & 31) * 4;
  const int rq   = t >> 5;              // 0..15 -> rows rq*2, rq*2+1
  float acc[2][4] = {};

  for (int k0 = 0; k0 < FIN; k0 += 64) {
    *(f32x4*)&hl[t >> 4][(t & 15) * 4] =
        *(const f32x4*)(h + (size_t)(i0 + (t >> 4)) * FIN + k0 + (t & 15) * 4);
#pragma unroll
    for (int j = 0; j < 4; ++j) {
      int c = t + 512 * j;
      int kr = c >> 5, f4 = (c & 31) * 4;
      *(f32x4*)&wl[kr][f4] = *(const f32x4*)(w + (size_t)(k0 + kr) * F + f4);
    }
    __syncthreads();
#pragma unroll 4
    for (int k4 = 0; k4 < 64; k4 += 4) {
      f32x4 wv[4];
#pragma unroll
      for (int u = 0; u < 4; ++u) wv[u] = *(const f32x4*)&wl[k4 + u][col4];
#pragma unroll
      for (int ri = 0; ri < 2; ++ri) {
        f32x4 hv = *(const f32x4*)&hl[rq * 2 + ri][k4];
#pragma unroll
        for (int u = 0; u < 4; ++u) {
#pragma unroll
          for (int ci = 0; ci < 4; ++ci) acc[ri][ci] += hv[u] * wv[u][ci];
        }
      }
    }
    __syncthreads();
  }
  {
    const int kt    = i0 >> 5;
    const int kslot = rq >> 2;
    const int u     = (rq * 2) & 7;
#pragma unroll
    for (int ci = 0; ci < 4; ++ci) {
      int f = col4 + ci;
      int nb = f >> 4, c = f & 15;
      unsigned pk = (unsigned)(unsigned short)f2bf(acc[0][ci]) |
                    ((unsigned)(unsigned short)f2bf(acc[1][ci]) << 16);
      size_t idx = (size_t)(kt * 8 + nb) * 512 + (kslot * 16 + c) * 8 + u;
      *(unsigned*)(Bpack + idx) = pk;
    }
  }
  f32x4 av1 = *(const f32x4*)(a + col4);
  f32x4 av2 = *(const f32x4*)(a + F + col4);
  float s1[2], s2[2];
#pragma unroll
  for (int ri = 0; ri < 2; ++ri) {
    s1[ri] = acc[ri][0] * av1[0] + acc[ri][1] * av1[1] +
             acc[ri][2] * av1[2] + acc[ri][3] * av1[3];
    s2[ri] = acc[ri][0] * av2[0] + acc[ri][1] * av2[1] +
             acc[ri][2] * av2[2] + acc[ri][3] * av2[3];
  }
#pragma unroll
  for (int off = 1; off < 32; off <<= 1) {
#pragma unroll
    for (int ri = 0; ri < 2; ++ri) {
      s1[ri] += __shfl_xor(s1[ri], off);
      s2[ri] += __shfl_xor(s2[ri], off);
    }
  }
  if ((t & 31) == 0) {
#pragma unroll
    for (int ri = 0; ri < 2; ++ri) {
      Wh1[i0 + rq * 2 + ri] = s1[ri];
      Wh2[i0 + rq * 2 + ri] = s2[ri];
    }
  }
}

// ---------------------------------------------------------------------------
// K2: fused GAT attention partials -- NO HBM in the loop, no barriers, no
// ballots. grid (128, KS), block 256 = 4 waves; wave owns 16 rows x 128 f,
// phases of 32 j. Per phase: 8 Bpack loads (L2-local, coalesced 1KB/instr,
// double-buffered one phase ahead) + one u64 bitmask per row per 2 phases
// (8 MB, L2/L3). Scores: p = maskbit ? exp(lrelu(Wh1+Wh2)) : 0 (bounded,
// no online max). Wh2 in LDS (lgkm path).
// ---------------------------------------------------------------------------
template <int KS>
__global__ __launch_bounds__(256) __attribute__((amdgpu_waves_per_eu(1, 4)))
void k_attn(
    const u64* __restrict__ mask, const float* __restrict__ Wh1v,
    const float* __restrict__ Wh2v, const short* __restrict__ Bpack,
    float* __restrict__ accP, float* __restrict__ lP) {
  constexpr int JW  = N / KS;
  constexpr int NTL = JW / 32;     // phases (32 for KS=8) -- even
  __shared__ float w2l[JW];

  const int t   = threadIdx.x;
  const int l   = t & 63;
  const int w   = t >> 6;
  const int r16 = l & 15;
  const int g8  = (l >> 4) * 8;
  const int i0  = blockIdx.x * BR;
  const int s   = blockIdx.y;

  const int row  = i0 + w * BRW + r16;
  const float w1 = Wh1v[row];
  const u64* __restrict__ mrow = mask + (size_t)row * (N / 64) + s * (JW / 64);
  const short* __restrict__ bq = Bpack + (size_t)s * NTL * 8 * 512 + l * 8;

  f32x4 acc[8] = {};
  float lsum = 0.f;
  s16x8 bfA[8], bfB[8];
  u64 mA, mB;

#define BF_LOAD(bf, tt)                                                      \
  _Pragma("unroll") for (int nb = 0; nb < 8; ++nb)                           \
      bf[nb] = *(const s16x8*)(bq + (size_t)((tt) * 8 + nb) * 512);

  auto scores8 = [&](unsigned mb, int tt, s16x8& af) {
    const f32x4 y0 = *(const f32x4*)&w2l[tt * 32 + g8];
    const f32x4 y1 = *(const f32x4*)&w2l[tt * 32 + g8 + 4];
    float p[8];
#pragma unroll
    for (int u = 0; u < 4; ++u) {
      float x = w1 + y0[u]; x = fmaxf(x, LRELU_ALPHA * x);
      p[u] = (mb >> u) & 1u ? __expf(x) : 0.f;
    }
#pragma unroll
    for (int u = 0; u < 4; ++u) {
      float x = w1 + y1[u]; x = fmaxf(x, LRELU_ALPHA * x);
      p[4 + u] = (mb >> (4 + u)) & 1u ? __expf(x) : 0.f;
    }
#pragma unroll
    for (int u = 0; u < 8; ++u) lsum += p[u];
    af = s16x8{f2bf(p[0]), f2bf(p[1]), f2bf(p[2]), f2bf(p[3]),
               f2bf(p[4]), f2bf(p[5]), f2bf(p[6]), f2bf(p[7])};
  };

  // ---- prologue: Wh2 -> LDS; bf(0); mask u64 for phases 0,1 ----
#pragma unroll
  for (int j4 = t; j4 < JW / 4; j4 += 256)
    *(f32x4*)&w2l[j4 * 4] = *(const f32x4*)(Wh2v + (size_t)s * JW + j4 * 4);
  BF_LOAD(bfA, 0)
  mA = mrow[0];
  __syncthreads();                 // one-time drain; regs stay valid

  for (int tt = 0; tt < NTL; tt += 2) {
    // ---- even phase tt: consume bfA + mA.lo; issue bfB(tt+1), m(tt+2) ----
    {
      BF_LOAD(bfB, tt + 1)                       // tt+1 < NTL (NTL even)
      if (tt + 2 < NTL) mB = mrow[tt / 2 + 1];
      s16x8 af;
      scores8((unsigned)(mA >> g8) & 0xffu, tt, af);
#pragma unroll
      for (int nb = 0; nb < 8; ++nb)
        acc[nb] = __builtin_amdgcn_mfma_f32_16x16x32_bf16(af, bfA[nb],
                                                          acc[nb], 0, 0, 0);
    }
    // ---- odd phase tt+1: consume bfB + mA.hi; issue bfA(tt+2) ----
    {
      if (tt + 2 < NTL) BF_LOAD(bfA, tt + 2)
      s16x8 af;
      scores8((unsigned)(mA >> (32 + g8)) & 0xffu, tt + 1, af);
#pragma unroll
      for (int nb = 0; nb < 8; ++nb)
        acc[nb] = __builtin_amdgcn_mfma_f32_16x16x32_bf16(af, bfB[nb],
                                                          acc[nb], 0, 0, 0);
      mA = mB;
    }
  }
#undef BF_LOAD

  // row-sums: lanes {l, l^16, l^32, l^48} hold the row's j-slot partials
  lsum += __shfl_xor(lsum, 16);
  lsum += __shfl_xor(lsum, 32);
  if (l < 16) lP[(size_t)s * N + row] = lsum;
  // partial accumulator (C layout: row=(l>>4)*4+rg, col=l&15)
  float* op = accP + (size_t)s * N * F;
#pragma unroll
  for (int nb = 0; nb < 8; ++nb) {
#pragma unroll
    for (int rg = 0; rg < 4; ++rg) {
      int r = i0 + w * BRW + (l >> 4) * 4 + rg;
      op[(size_t)r * F + nb * 16 + r16] = acc[nb][rg];
    }
  }
}

// ---------------------------------------------------------------------------
// K3: combine partials: out = elu( (sum_s accP) / (sum_s lP) )
// ---------------------------------------------------------------------------
template <int KS>
__global__ __launch_bounds__(256) void k_comb(
    const float* __restrict__ accP, const float* __restrict__ lP,
    float* __restrict__ out) {
  const int idx = blockIdx.x * 256 + threadIdx.x;  // one f32x4 per thread
  const int i   = idx >> 5;                        // row (F/4 = 32 per row)
  f32x4 v = {};
  float lt = 0.f;
#pragma unroll
  for (int s = 0; s < KS; ++s) {
    v += *(const f32x4*)(accP + (size_t)s * N * F + (size_t)idx * 4);
    lt += lP[(size_t)s * N + i];
  }
  f32x4 o;
#pragma unroll
  for (int u = 0; u < 4; ++u) {
    float x = v[u] / lt;
    o[u] = x > 0.f ? x : __expf(x) - 1.f;          // ELU
  }
  *(f32x4*)(out + (size_t)idx * 4) = o;
}

// ---------------------------------------------------------------------------
extern "C" void kernel_launch(void* const* d_in, const int* in_sizes, int n_in,
                              void* d_out, int out_size, void* d_ws, size_t ws_size,
                              hipStream_t stream) {
  const float* h   = (const float*)d_in[0];
  const int*   adj = (const int*)d_in[1];
  const float* w   = (const float*)d_in[2];
  const float* a   = (const float*)d_in[3];
  float* out = (float*)d_out;

  // ws: Bpack bf16 (2 MB) | Wh1 [N] | Wh2 [N] | mask [N][N/64] u64 (8 MB)
  //     | lP [KS][N] | accP [KS][N][F]
  char* ws = (char*)d_ws;
  short* Bpack = (short*)ws;
  float* Wh1 = (float*)(ws + (size_t)F * N * 2);
  float* Wh2 = Wh1 + N;
  u64*  mask = (u64*)(Wh2 + N);
  float* lP  = (float*)(mask + (size_t)N * (N / 64));

  const size_t fixed = (size_t)F * N * 2 + 2 * (size_t)N * 4 +
                       (size_t)N * (N / 64) * 8;
  const size_t need8 = fixed + 8 * (size_t)N * 4 + 8 * (size_t)N * F * 4;

  k_prod<<<1280, 512, 0, stream>>>(h, w, a, adj, Bpack, Wh1, Wh2, mask);
  if (ws_size >= need8) {
    constexpr int KS = 8;
    float* accP = lP + (size_t)KS * N;
    k_attn<KS><<<dim3(N / BR, KS), 256, 0, stream>>>(mask, Wh1, Wh2, Bpack,
                                                     accP, lP);
    k_comb<KS><<<(N * F / 4) / 256, 256, 0, stream>>>(accP, lP, out);
  } else {
    constexpr int KS = 4;
    float* accP = lP + (size_t)KS * N;
    k_attn<KS><<<dim3(N / BR, KS), 256, 0, stream>>>(mask, Wh1, Wh2, Bpack,
                                                     accP, lP);
    k_comb<KS><<<(N * F / 4) / 256, 256, 0, stream>>>(accP, lP, out);
  }
}